// Round 6
// baseline (313.035 us; speedup 1.0000x reference)
//
#include <hip/hip_runtime.h>

// Sequential2D: out[i] = sum_{j in [max(0,i-2), i]} X[j] @ W[i,j]^T + sum_j b[i,j]
// X (8,32768,128) f32, W (8,8,128,128) f32, b (8,8,128) f32, out (8,32768,128) f32.
//
// R8: pinned prefetch ring. Counter history (VGPR 84/128/60 in R3/R4/R5) shows
// the compiler was SINKING the prefetch loads to their uses — the ring never
// existed, so every k-step ate full memory latency. Fix: ring loads via inline
// asm global_load_dwordx4 (volatile => cannot be sunk) + manual counted vmcnt.
// After the single prologue __syncthreads, the main loop's only VMEM is the
// asm ring => static counts exact: vmcnt(12) steady, 12/8/4/0 in last phase.
// W: one 32KB XOR-swizzled LDS buffer; W[jlo] staged directly, W[jlo+1/2]
// pre-converted to bf16 regs, restaged reg->LDS between raw s_barriers with
// lgkm-only drain (no VMEM consumed mid-loop => ring never drained).
// LDS 33KB, 256 thr, 2 wg/CU.

#define NOUT  8
#define NIN   8
#define DD    128
#define BATCH 32768
#define BAND  2
#define BM    128                 // batch rows per wg (4 waves x 32 rows)
#define XSTRIDE ((size_t)BATCH * DD)

typedef __attribute__((ext_vector_type(8))) short  short8;
typedef __attribute__((ext_vector_type(4))) float  floatx4;

__device__ __forceinline__ unsigned short f2bf(float f) {
    unsigned int u = __float_as_uint(f);
    u += 0x7fffu + ((u >> 16) & 1u);
    return (unsigned short)(u >> 16);
}

__device__ __forceinline__ short8 pack8(floatx4 f0, floatx4 f1) {
    short8 p;
    p[0] = (short)f2bf(f0[0]); p[1] = (short)f2bf(f0[1]);
    p[2] = (short)f2bf(f0[2]); p[3] = (short)f2bf(f0[3]);
    p[4] = (short)f2bf(f1[0]); p[5] = (short)f2bf(f1[1]);
    p[6] = (short)f2bf(f1[2]); p[7] = (short)f2bf(f1[3]);
    return p;
}

// One k-step: wait (manual, counted) -> consume slot ks -> reissue (asm, pinned)
// -> 16 MFMAs against the LDS-resident W tile.
#define KSTEP(ks, WAITN, PNEXT, REISSUE)                                        \
  {                                                                             \
    asm volatile("s_waitcnt vmcnt(" #WAITN ")");                                \
    __builtin_amdgcn_sched_barrier(0);                                          \
    short8 a0 = pack8(px[ks][0][0], px[ks][0][1]);                              \
    short8 a1 = pack8(px[ks][1][0], px[ks][1][1]);                              \
    if (REISSUE) {                                                              \
      const float* p_ = (PNEXT) + (ks) * 32;                                    \
      asm volatile("global_load_dwordx4 %0, %4, off\n\t"                        \
                   "global_load_dwordx4 %1, %4, off offset:16\n\t"              \
                   "global_load_dwordx4 %2, %5, off\n\t"                        \
                   "global_load_dwordx4 %3, %5, off offset:16"                  \
                   : "=&v"(px[ks][0][0]), "=&v"(px[ks][0][1]),                  \
                     "=&v"(px[ks][1][0]), "=&v"(px[ks][1][1])                   \
                   : "v"(p_), "v"(p_ + 16 * DD));                               \
    }                                                                           \
    _Pragma("unroll")                                                           \
    for (int nf = 0; nf < 8; ++nf) {                                            \
      const short8 bfrag = *(const short8*)                                     \
          &sW[(nf * 16 + l15) * 128 + ((((ks) * 4 + quad) ^ l15) << 3)];        \
      acc[0][nf] = __builtin_amdgcn_mfma_f32_16x16x32_bf16(a0, bfrag, acc[0][nf], 0, 0, 0); \
      acc[1][nf] = __builtin_amdgcn_mfma_f32_16x16x32_bf16(a1, bfrag, acc[1][nf], 0, 0, 0); \
    }                                                                           \
  }

#define PHASE_MID(PN)  { KSTEP(0,12,PN,1) KSTEP(1,12,PN,1) KSTEP(2,12,PN,1) KSTEP(3,12,PN,1) }
#define PHASE_LAST()   { KSTEP(0,12,xb,0) KSTEP(1, 8,xb,0) KSTEP(2, 4,xb,0) KSTEP(3, 0,xb,0) }

// reg->LDS restage of the next W block between raw barriers; lgkm-only drain,
// the asm ring's global loads stay in flight across both barriers.
#define RESTAGE(WREGS)                                                          \
  {                                                                             \
    __builtin_amdgcn_sched_barrier(0);                                          \
    __builtin_amdgcn_s_barrier();                                               \
    __builtin_amdgcn_sched_barrier(0);                                          \
    unsigned short* sb_ = &sW[wr_r * 128];                                      \
    _Pragma("unroll")                                                           \
    for (int w_ = 0; w_ < 8; ++w_)                                              \
      *(short8*)&sb_[(((wr_cb0 + w_) ^ (wr_r & 15)) << 3)] = WREGS[w_];         \
    __builtin_amdgcn_sched_barrier(0);                                          \
    asm volatile("s_waitcnt lgkmcnt(0)");                                       \
    __builtin_amdgcn_sched_barrier(0);                                          \
    __builtin_amdgcn_s_barrier();                                               \
    __builtin_amdgcn_sched_barrier(0);                                          \
  }

__global__ __launch_bounds__(256, 2)
void seq2d_kernel(const float* __restrict__ X,
                  const float* __restrict__ W,
                  const float* __restrict__ Bv,
                  float* __restrict__ out) {
    const int i  = blockIdx.y;
    const int m0 = blockIdx.x * BM;

    __shared__ unsigned short sW[DD * 128];   // 32 KB, XOR-swizzled
    __shared__ float sbias[DD];

    const int tid  = threadIdx.x;
    const int lane = tid & 63;
    const int wave = tid >> 6;          // 0..3, each owns 32 batch rows
    const int l15  = lane & 15;
    const int quad = lane >> 4;

    int jlo = i - BAND; if (jlo < 0) jlo = 0;
    const int nj = i - jlo + 1;         // 1..3 active j-blocks

    // Per-lane A base: row = m0 + wave*32 + (lane&15), k-offset quad*8.
    const float* xb = X + (size_t)(m0 + wave * 32 + l15) * DD + quad * 8;

    // Prologue ring fill (normal loads; drained once by __syncthreads, data
    // lands in px regs; main loop reissues via pinned asm loads).
    floatx4 px[4][2][2];
#pragma unroll
    for (int ks = 0; ks < 4; ++ks) {
        const float* p = xb + (size_t)jlo * XSTRIDE + ks * 32;
        px[ks][0][0] = *(const floatx4*)(p);
        px[ks][0][1] = *(const floatx4*)(p + 4);
        px[ks][1][0] = *(const floatx4*)(p + 16 * DD);
        px[ks][1][1] = *(const floatx4*)(p + 16 * DD + 4);
    }

    if (tid < DD) {
        float s = 0.f;
        for (int j = jlo; j <= i; ++j)
            s += Bv[(i * NIN + j) * DD + tid];
        sbias[tid] = s;
    }

    // W staging geometry: thread t -> row t>>1 (0..127), col-blocks of 8 shorts
    // starting at (t&1)*8; physical col-block = cb ^ (row & 15)  (XOR swizzle,
    // conflict-free b128 reads at stride 256 B).
    const int wr_r   = tid >> 1;
    const int wr_cb0 = (tid & 1) * 8;

    {   // W[jlo] -> LDS directly
        const float* ws = W + (size_t)(i * NIN + jlo) * DD * DD
                            + (size_t)wr_r * DD + wr_cb0 * 8;
        unsigned short* sb = &sW[wr_r * 128];
#pragma unroll
        for (int w = 0; w < 8; ++w) {
            floatx4 a = *(const floatx4*)(ws + w * 8);
            floatx4 b = *(const floatx4*)(ws + w * 8 + 4);
            *(short8*)&sb[(((wr_cb0 + w) ^ (wr_r & 15)) << 3)] = pack8(a, b);
        }
    }

    // W[jlo+1], W[jlo+2] pre-converted to bf16, held in regs (16 VGPR each).
    short8 w1s[8], w2s[8];
    if (nj >= 2) {
        const float* ws = W + (size_t)(i * NIN + jlo + 1) * DD * DD
                            + (size_t)wr_r * DD + wr_cb0 * 8;
#pragma unroll
        for (int w = 0; w < 8; ++w) {
            floatx4 a = *(const floatx4*)(ws + w * 8);
            floatx4 b = *(const floatx4*)(ws + w * 8 + 4);
            w1s[w] = pack8(a, b);
        }
    }
    if (nj >= 3) {
        const float* ws = W + (size_t)(i * NIN + jlo + 2) * DD * DD
                            + (size_t)wr_r * DD + wr_cb0 * 8;
#pragma unroll
        for (int w = 0; w < 8; ++w) {
            floatx4 a = *(const floatx4*)(ws + w * 8);
            floatx4 b = *(const floatx4*)(ws + w * 8 + 4);
            w2s[w] = pack8(a, b);
        }
    }

    __syncthreads();   // one-time full drain; after this, outstanding VMEM = 0.

    floatx4 acc[2][8];
#pragma unroll
    for (int a = 0; a < 2; ++a)
#pragma unroll
        for (int n = 0; n < 8; ++n)
            acc[a][n] = (floatx4){0.f, 0.f, 0.f, 0.f};

    // Main loop: nj phases of 4 k-steps (K=32). Only VMEM = pinned asm ring.
    if (nj == 1) {
        PHASE_LAST();
    } else if (nj == 2) {
        const float* p1 = xb + (size_t)(jlo + 1) * XSTRIDE;
        PHASE_MID(p1);
        RESTAGE(w1s);
        PHASE_LAST();
    } else {
        const float* p1 = xb + (size_t)(jlo + 1) * XSTRIDE;
        const float* p2 = xb + (size_t)(jlo + 2) * XSTRIDE;
        PHASE_MID(p1);
        RESTAGE(w1s);
        PHASE_MID(p2);
        RESTAGE(w2s);
        PHASE_LAST();
    }

    // epilogue: C/D layout row=(lane>>4)*4+r, col=lane&15 (verified R1).
    float* outi = out + (size_t)i * BATCH * DD;
#pragma unroll
    for (int mf = 0; mf < 2; ++mf) {
        const int m_b = m0 + wave * 32 + mf * 16 + quad * 4;
#pragma unroll
        for (int nf = 0; nf < 8; ++nf) {
            const int n_g  = nf * 16 + l15;
            const float bs = sbias[n_g];
#pragma unroll
            for (int r = 0; r < 4; ++r)
                outi[(size_t)(m_b + r) * DD + n_g] = acc[mf][nf][r] + bs;
        }
    }
}

extern "C" void kernel_launch(void* const* d_in, const int* in_sizes, int n_in,
                              void* d_out, int out_size, void* d_ws, size_t ws_size,
                              hipStream_t stream) {
    const float* X  = (const float*)d_in[0];
    const float* W  = (const float*)d_in[1];
    const float* Bv = (const float*)d_in[2];
    float* out = (float*)d_out;

    dim3 grid(BATCH / BM, NOUT);
    seq2d_kernel<<<grid, 256, 0, stream>>>(X, W, Bv, out);
}